// Round 1
// baseline (744.767 us; speedup 1.0000x reference)
//
#include <hip/hip_runtime.h>
#include <cfloat>

// Problem constants
#define BB 64          // batch
#define CC 2048        // x channels
#define AR 2048        // x_art channels
#define DD 4096        // CC + AR
#define VV 256         // views
#define FF 4096        // hidden
#define OO 1000        // out channels

// ---------------------------------------------------------------------------
// Kernel 1: ragged max-pool over views -> pooled TRANSPOSED [D][64].
// (unchanged from previous best — memory-bound, reads only the live prefix)
// ---------------------------------------------------------------------------
__global__ __launch_bounds__(256) void pool_kernel(
    const float* __restrict__ x, const float* __restrict__ xart,
    const int* __restrict__ ll, float* __restrict__ pooledT)
{
    int waveId = (blockIdx.x * 256 + threadIdx.x) >> 6;   // 0..8191
    int lane   = threadIdx.x & 63;
    int row0   = waveId * 32;                             // 32 rows per wave
    int b  = row0 >> 12;
    int d0 = row0 & 4095;
    int len = ll[b];
    if (len < 1) len = 1;
    const float* base = (d0 < CC)
        ? (x    + ((size_t)b * CC + d0)        * VV)
        : (xart + ((size_t)b * AR + (d0 - CC)) * VV);
    int v0  = lane * 4;
    int rem = len - v0;           // >0 means lane active; same for all 32 rows

    for (int r = 0; r < 32; r += 4) {
        const float* s = base + (size_t)r * VV;
        float m0 = -FLT_MAX, m1 = -FLT_MAX, m2 = -FLT_MAX, m3 = -FLT_MAX;
        if (rem > 0) {
            float4 a0 = *(const float4*)(s + v0);
            float4 a1 = *(const float4*)(s + VV + v0);
            float4 a2 = *(const float4*)(s + 2 * VV + v0);
            float4 a3 = *(const float4*)(s + 3 * VV + v0);
            m0 = a0.x; m1 = a1.x; m2 = a2.x; m3 = a3.x;
            if (rem > 1) { m0 = fmaxf(m0, a0.y); m1 = fmaxf(m1, a1.y);
                           m2 = fmaxf(m2, a2.y); m3 = fmaxf(m3, a3.y); }
            if (rem > 2) { m0 = fmaxf(m0, a0.z); m1 = fmaxf(m1, a1.z);
                           m2 = fmaxf(m2, a2.z); m3 = fmaxf(m3, a3.z); }
            if (rem > 3) { m0 = fmaxf(m0, a0.w); m1 = fmaxf(m1, a1.w);
                           m2 = fmaxf(m2, a2.w); m3 = fmaxf(m3, a3.w); }
        }
        #pragma unroll
        for (int off = 32; off > 0; off >>= 1) {
            m0 = fmaxf(m0, __shfl_xor(m0, off, 64));
            m1 = fmaxf(m1, __shfl_xor(m1, off, 64));
            m2 = fmaxf(m2, __shfl_xor(m2, off, 64));
            m3 = fmaxf(m3, __shfl_xor(m3, off, 64));
        }
        float wv = m0;
        if (lane == 1) wv = m1;
        else if (lane == 2) wv = m2;
        else if (lane == 3) wv = m3;
        if (lane < 4)
            pooledT[(size_t)(d0 + r + lane) * 64 + b] = wv;
    }
}

// ---------------------------------------------------------------------------
// Kernel 2: LDS-free skinny split-K GEMM.  lane = batch (M=64 = wave width).
// Each wave owns FT=32 f-columns x one K-chunk:
//   per k: 1 coalesced dword load of PT[k][lane]   (256 B/wave, L2-resident)
//          8 lane-uniform float4 loads of W[k][f0..f0+31] (broadcast -> 1 txn)
//          32 v_fmac into acc[32]
// Distance-1 software prefetch hides L2 latency (4 waves/SIMD * 64 cyc FMA
// per k = 256 cyc coverage vs ~200 cyc L2 hit).
// No LDS, no __syncthreads: removes the 117 TB/s LDS demand of the previous
// tile kernel (LDS ceiling 69 TB/s) -> VALU-bound at the 13.7 us f32 floor.
// Output partial is TRANSPOSED: part[chunk][f][64].
// F tail (layer 3, F=1000): only the last f-tile is masked; the branch is
// wave-uniform and hoisted out of the k-loop.
// ---------------------------------------------------------------------------
#define FT 32

__global__ __launch_bounds__(256, 4) void gemm_skinny(
    const float* __restrict__ P,    // [K][64]  transposed activations
    const float* __restrict__ W,    // [K][F]   row-major weights
    float* __restrict__ part,       // [KSPLIT][F][64]
    int F, int kchunk)
{
    int winb = threadIdx.x >> 6;                  // wave in block: 0..3
    int lane = threadIdx.x & 63;                  // = batch b
    int f0   = (blockIdx.x * 4 + winb) * FT;
    int k0   = blockIdx.y * kchunk;

    const float* prow = P + (size_t)k0 * 64 + lane;
    const float* wrow = W + (size_t)k0 * F + f0;

    float acc[FT];
    #pragma unroll
    for (int j = 0; j < FT; ++j) acc[j] = 0.f;

    if (f0 + FT <= F) {
        // ---- full tile: software-pipelined main path ----
        float pv = prow[0];
        float4 wv[FT / 4];
        #pragma unroll
        for (int q = 0; q < FT / 4; ++q)
            wv[q] = *(const float4*)(wrow + 4 * q);

        for (int k = 0; k < kchunk - 1; ++k) {
            float pn = prow[(size_t)(k + 1) * 64];
            const float* wr = wrow + (size_t)(k + 1) * F;
            float4 wn[FT / 4];
            #pragma unroll
            for (int q = 0; q < FT / 4; ++q)
                wn[q] = *(const float4*)(wr + 4 * q);
            #pragma unroll
            for (int q = 0; q < FT / 4; ++q) {
                acc[4 * q + 0] += pv * wv[q].x;
                acc[4 * q + 1] += pv * wv[q].y;
                acc[4 * q + 2] += pv * wv[q].z;
                acc[4 * q + 3] += pv * wv[q].w;
            }
            pv = pn;
            #pragma unroll
            for (int q = 0; q < FT / 4; ++q) wv[q] = wn[q];
        }
        #pragma unroll
        for (int q = 0; q < FT / 4; ++q) {
            acc[4 * q + 0] += pv * wv[q].x;
            acc[4 * q + 1] += pv * wv[q].y;
            acc[4 * q + 2] += pv * wv[q].z;
            acc[4 * q + 3] += pv * wv[q].w;
        }
        float* dst = part + ((size_t)blockIdx.y * F + f0) * 64 + lane;
        #pragma unroll
        for (int j = 0; j < FT; ++j)
            dst[(size_t)j * 64] = acc[j];
    } else {
        // ---- tail tile (layer 3 only: f0=992, F=1000) ----
        for (int k = 0; k < kchunk; ++k) {
            float pv = prow[(size_t)k * 64];
            const float* wr = wrow + (size_t)k * F;
            #pragma unroll
            for (int j = 0; j < FT; ++j)
                if (f0 + j < F) acc[j] += pv * wr[j];
        }
        float* dst = part + ((size_t)blockIdx.y * F + f0) * 64 + lane;
        #pragma unroll
        for (int j = 0; j < FT; ++j)
            if (f0 + j < F) dst[(size_t)j * 64] = acc[j];
    }
}

// ---------------------------------------------------------------------------
// Kernel 3: reduce split-K partials + bias + ReLU -> TRANSPOSED [F][64].
// Partials are already transposed [c][f][64], so no LDS transpose needed:
// thread (fl, lane) sums over chunks with 256 B coalesced rows.
// ---------------------------------------------------------------------------
__global__ __launch_bounds__(256) void reduce_bias_relu_T(
    const float* __restrict__ part, const float* __restrict__ bias,
    float* __restrict__ outT, int nchunk, int F)
{
    int lane = threadIdx.x & 63;
    int fl   = threadIdx.x >> 6;          // 0..3
    int f    = blockIdx.x * 4 + fl;
    float acc = bias[f];
    const float* p = part + (size_t)f * 64 + lane;
    size_t stride = (size_t)F * 64;
    #pragma unroll 8
    for (int c = 0; c < nchunk; ++c)
        acc += p[(size_t)c * stride];
    outT[(size_t)f * 64 + lane] = fmaxf(acc, 0.f);
}

// ---------------------------------------------------------------------------
// Kernel 4: final reduce + bias (no ReLU) -> d_out [64][1000].
// Partials [c][f][64]: reads coalesced (lane = batch), writes scattered
// (256 KB total -- negligible).
// ---------------------------------------------------------------------------
__global__ __launch_bounds__(256) void reduce_out_kernel(
    const float* __restrict__ part, const float* __restrict__ bias,
    float* __restrict__ out, int nchunk)
{
    int idx = blockIdx.x * 256 + threadIdx.x;    // f*64 + b
    if (idx >= OO * 64) return;
    int f = idx >> 6, b = idx & 63;
    float v = bias[f];
    const float* p = part + (size_t)f * 64 + b;
    size_t stride = (size_t)OO * 64;
    #pragma unroll 8
    for (int c = 0; c < nchunk; ++c)
        v += p[(size_t)c * stride];
    out[(size_t)b * OO + f] = v;
}

// ---------------------------------------------------------------------------
extern "C" void kernel_launch(void* const* d_in, const int* in_sizes, int n_in,
                              void* d_out, int out_size, void* d_ws, size_t ws_size,
                              hipStream_t stream) {
    const float* x    = (const float*)d_in[0];
    const float* xart = (const float*)d_in[1];
    const int*   ll   = (const int*)d_in[2];
    const float* w1   = (const float*)d_in[3];
    const float* b1   = (const float*)d_in[4];
    const float* w2   = (const float*)d_in[5];
    const float* b2   = (const float*)d_in[6];
    const float* w3   = (const float*)d_in[7];
    const float* b3   = (const float*)d_in[8];
    float* out = (float*)d_out;

    // workspace: pooledT 1MiB | h1T 1MiB | h2T 1MiB | part (split-K partials)
    float* pooledT = (float*)d_ws;
    float* h1T     = pooledT + (size_t)DD * 64;
    float* h2T     = h1T     + (size_t)FF * 64;
    float* part    = h2T     + (size_t)FF * 64;

    // adapt split-K factor to available workspace (deterministic per session)
    size_t actBytes = (size_t)(DD + FF + FF) * 64 * sizeof(float);   // 3 MiB
    size_t avail    = (ws_size > actBytes) ? ws_size - actBytes : 0;
    size_t plane1   = (size_t)64 * FF * sizeof(float);               // 1 MiB
    int nk1 = 8;
    if (avail >= 32 * plane1)      nk1 = 32;   // 1024 blocks: 4 blocks/CU
    else if (avail >= 16 * plane1) nk1 = 16;
    size_t plane3 = (size_t)64 * OO * sizeof(float);                 // 250 KiB
    int nk3 = (avail >= 64 * plane3) ? 64 : 32;
    int kchunk1 = DD / nk1;
    int kchunk3 = FF / nk3;

    // 1) ragged max-pool -> pooledT [4096][64]
    pool_kernel<<<2048, 256, 0, stream>>>(x, xart, ll, pooledT);

    // 2) h1 = relu(pooled @ w1 + b1)    (FF/FT/4 = 32 blocks in x)
    gemm_skinny<<<dim3(FF / (FT * 4), nk1), 256, 0, stream>>>(pooledT, w1, part, FF, kchunk1);
    reduce_bias_relu_T<<<FF / 4, 256, 0, stream>>>(part, b1, h1T, nk1, FF);

    // 3) h2 = relu(h1 @ w2 + b2)
    gemm_skinny<<<dim3(FF / (FT * 4), nk1), 256, 0, stream>>>(h1T, w2, part, FF, kchunk1);
    reduce_bias_relu_T<<<FF / 4, 256, 0, stream>>>(part, b2, h2T, nk1, FF);

    // 4) out = h2 @ w3 + b3   (ceil(1000/32)=32 tiles -> 8 blocks in x)
    gemm_skinny<<<dim3(8, nk3), 256, 0, stream>>>(h2T, w3, part, OO, kchunk3);
    reduce_out_kernel<<<(BB * OO + 255) / 256, 256, 0, stream>>>(part, b3, out, nk3);
}

// Round 2
// 400.350 us; speedup vs baseline: 1.8603x; 1.8603x over previous
//
#include <hip/hip_runtime.h>
#include <cfloat>

// Problem constants
#define BB 64          // batch
#define CC 2048        // x channels
#define AR 2048        // x_art channels
#define DD 4096        // CC + AR
#define VV 256         // views
#define FF 4096        // hidden
#define OO 1000        // out channels

typedef float f32x4 __attribute__((ext_vector_type(4)));
typedef short bfrag __attribute__((ext_vector_type(8)));   // 8 bf16 = 4 VGPRs

// Split f32 -> bf16 hi + bf16 lo (RNE both).  a ~= hi + lo to ~2^-17 rel.
__device__ inline void bf16split(float x, unsigned short &hi, unsigned short &lo) {
    unsigned int u = __float_as_uint(x);
    unsigned int r = (u + 0x7FFFu + ((u >> 16) & 1u)) >> 16;
    hi = (unsigned short)r;
    float hf = __uint_as_float(r << 16);
    float rem = x - hf;
    unsigned int u2 = __float_as_uint(rem);
    unsigned int r2 = (u2 + 0x7FFFu + ((u2 >> 16) & 1u)) >> 16;
    lo = (unsigned short)r2;
}

// A-fragment linear index for mfma_f32_16x16x32_bf16.
// Element (k, b):  frag (kstep=k>>5, mstrip=b>>4), lane l = (b&15)+16*((k&31)>>3),
// elem j = k&7.  Layout: [kstep][mstrip][lane][8]  (16B per lane per frag).
__device__ inline size_t fragIdx(int k, int b) {
    int kk = k & 31;
    return ((size_t)((k >> 5) * 4 + (b >> 4))) * 512
         + (size_t)((((b & 15) + ((kk >> 3) << 4)) << 3) + (kk & 7));
}

// ---------------------------------------------------------------------------
// Kernel 1: ragged max-pool over views -> A1 fragments (bf16 hi/lo).
// Pooling logic unchanged from the verified round-0 kernel; only the final
// write changed: split to bf16 hi/lo and store in MFMA A-frag layout.
// ---------------------------------------------------------------------------
__global__ __launch_bounds__(256) void pool_kernel(
    const float* __restrict__ x, const float* __restrict__ xart,
    const int* __restrict__ ll,
    unsigned short* __restrict__ Ahi, unsigned short* __restrict__ Alo)
{
    int waveId = (blockIdx.x * 256 + threadIdx.x) >> 6;   // 0..8191
    int lane   = threadIdx.x & 63;
    int row0   = waveId * 32;                             // 32 rows per wave
    int b  = row0 >> 12;
    int d0 = row0 & 4095;
    int len = ll[b];
    if (len < 1) len = 1;
    const float* base = (d0 < CC)
        ? (x    + ((size_t)b * CC + d0)        * VV)
        : (xart + ((size_t)b * AR + (d0 - CC)) * VV);
    int v0  = lane * 4;
    int rem = len - v0;           // >0 means lane active; same for all 32 rows

    for (int r = 0; r < 32; r += 4) {
        const float* s = base + (size_t)r * VV;
        float m0 = -FLT_MAX, m1 = -FLT_MAX, m2 = -FLT_MAX, m3 = -FLT_MAX;
        if (rem > 0) {
            float4 a0 = *(const float4*)(s + v0);
            float4 a1 = *(const float4*)(s + VV + v0);
            float4 a2 = *(const float4*)(s + 2 * VV + v0);
            float4 a3 = *(const float4*)(s + 3 * VV + v0);
            m0 = a0.x; m1 = a1.x; m2 = a2.x; m3 = a3.x;
            if (rem > 1) { m0 = fmaxf(m0, a0.y); m1 = fmaxf(m1, a1.y);
                           m2 = fmaxf(m2, a2.y); m3 = fmaxf(m3, a3.y); }
            if (rem > 2) { m0 = fmaxf(m0, a0.z); m1 = fmaxf(m1, a1.z);
                           m2 = fmaxf(m2, a2.z); m3 = fmaxf(m3, a3.z); }
            if (rem > 3) { m0 = fmaxf(m0, a0.w); m1 = fmaxf(m1, a1.w);
                           m2 = fmaxf(m2, a2.w); m3 = fmaxf(m3, a3.w); }
        }
        #pragma unroll
        for (int off = 32; off > 0; off >>= 1) {
            m0 = fmaxf(m0, __shfl_xor(m0, off, 64));
            m1 = fmaxf(m1, __shfl_xor(m1, off, 64));
            m2 = fmaxf(m2, __shfl_xor(m2, off, 64));
            m3 = fmaxf(m3, __shfl_xor(m3, off, 64));
        }
        float wv = m0;
        if (lane == 1) wv = m1;
        else if (lane == 2) wv = m2;
        else if (lane == 3) wv = m3;
        if (lane < 4) {
            int k = d0 + r + lane;
            unsigned short hi, lo;
            bf16split(wv, hi, lo);
            size_t idx = fragIdx(k, b);
            Ahi[idx] = hi;
            Alo[idx] = lo;
        }
    }
}

// ---------------------------------------------------------------------------
// Kernel 2: bf16x3 MFMA split-K GEMM, zero LDS.
// C[64][F] = A[64][K] * W[K][F], A given as preconverted hi/lo fragments.
// Block = 4 waves; wave w owns N-tile f0 = bx*64 + 16w and ALL 4 M-strips.
// B-fragment trick: lane l of wave w needs exactly W[k+(l>>4)*8+j][f0+(l&15)]
// -- loaded straight into that lane's registers (8 scalar dwords, 4x64B
// dense segments per instr). No LDS, no barriers, no broadcast loads.
// Per K32 step: 8 W loads (prefetched 1 step ahead), 8 A-frag loads (L2-hot,
// 1 MiB total), bf16 split (~50 VALU), 12 MFMA (hi*hi + hi*lo + lo*hi).
// MFMA headroom 4x over the W stream -> W-stream-bound (~11 us / 64 MiB).
// Output partial TRANSPOSED: part[chunk][f][64].
// ---------------------------------------------------------------------------
__global__ __launch_bounds__(256) void gemm_mfma(
    const unsigned short* __restrict__ Ahi, const unsigned short* __restrict__ Alo,
    const float* __restrict__ W, float* __restrict__ part,
    int F, int kchunk)
{
    int w = threadIdx.x >> 6;
    int l = threadIdx.x & 63;
    int f0  = blockIdx.x * 64 + w * 16;
    int col = f0 + (l & 15);
    bool cval = col < F;
    int k0 = blockIdx.y * kchunk;
    int kb = (l >> 4) * 8;                       // per-lane k offset in B frag

    const unsigned short* pAh = Ahi + ((size_t)(k0 >> 5) * 4) * 512 + l * 8;
    const unsigned short* pAl = Alo + ((size_t)(k0 >> 5) * 4) * 512 + l * 8;
    const float* wp = W + (size_t)(k0 + kb) * F + col;

    f32x4 zero = {0.f, 0.f, 0.f, 0.f};
    f32x4 acc[4];
    #pragma unroll
    for (int m = 0; m < 4; ++m) acc[m] = zero;

    int nsteps = kchunk >> 5;

    // prefetch step 0 W
    float wv[8];
    #pragma unroll
    for (int j = 0; j < 8; ++j)
        wv[j] = cval ? wp[(size_t)j * F] : 0.f;

    for (int s = 0; s < nsteps; ++s) {
        // A fragments for this step (L2-resident, issued early)
        bfrag ahi[4], alo[4];
        const unsigned short* pa = pAh + (size_t)s * 2048;
        const unsigned short* pb = pAl + (size_t)s * 2048;
        #pragma unroll
        for (int m = 0; m < 4; ++m) {
            ahi[m] = *(const bfrag*)(pa + m * 512);
            alo[m] = *(const bfrag*)(pb + m * 512);
        }
        // convert W to hi/lo B fragments
        bfrag bhi, blo;
        #pragma unroll
        for (int j = 0; j < 8; ++j) {
            float xv = wv[j];
            unsigned int u = __float_as_uint(xv);
            unsigned int r = (u + 0x7FFFu + ((u >> 16) & 1u)) >> 16;
            float hf = __uint_as_float(r << 16);
            float rem = xv - hf;
            unsigned int u2 = __float_as_uint(rem);
            unsigned int r2 = (u2 + 0x7FFFu + ((u2 >> 16) & 1u)) >> 16;
            bhi[j] = (short)r;
            blo[j] = (short)r2;
        }
        // prefetch next step W (keeps ~2KB/wave in flight during compute)
        if (s + 1 < nsteps) {
            const float* wn = wp + (size_t)(s + 1) * 32 * F;
            #pragma unroll
            for (int j = 0; j < 8; ++j)
                wv[j] = cval ? wn[(size_t)j * F] : 0.f;
        }
        #pragma unroll
        for (int m = 0; m < 4; ++m) {
            acc[m] = __builtin_amdgcn_mfma_f32_16x16x32_bf16(ahi[m], bhi, acc[m], 0, 0, 0);
            acc[m] = __builtin_amdgcn_mfma_f32_16x16x32_bf16(alo[m], bhi, acc[m], 0, 0, 0);
            acc[m] = __builtin_amdgcn_mfma_f32_16x16x32_bf16(ahi[m], blo, acc[m], 0, 0, 0);
        }
    }

    // D layout (m89-verified): row = mstrip*16 + (l>>4)*4 + reg, col = l&15.
    // part plane [F][64]: addr = col*64 + row -> reg-contiguous dwordx4.
    if (cval) {
        float* dst = part + (size_t)blockIdx.y * F * 64 + (size_t)col * 64 + (l >> 4) * 4;
        #pragma unroll
        for (int m = 0; m < 4; ++m)
            *(f32x4*)(dst + m * 16) = acc[m];
    }
}

// ---------------------------------------------------------------------------
// Kernel 3: reduce split-K partials + bias + ReLU -> next layer's A frags.
// Partials are [c][f][64]; thread (f, lane=b) sums chunks (coalesced 256B
// rows), applies bias+relu, splits to bf16 hi/lo, writes frag layout.
// ---------------------------------------------------------------------------
__global__ __launch_bounds__(256) void reduce_bias_relu_frag(
    const float* __restrict__ part, const float* __restrict__ bias,
    unsigned short* __restrict__ Ahi, unsigned short* __restrict__ Alo,
    int nchunk, int F)
{
    int lane = threadIdx.x & 63;          // batch b
    int fl   = threadIdx.x >> 6;          // 0..3
    int f    = blockIdx.x * 4 + fl;       // k of next layer
    float acc = bias[f];
    const float* p = part + (size_t)f * 64 + lane;
    size_t stride = (size_t)F * 64;
    #pragma unroll 8
    for (int c = 0; c < nchunk; ++c)
        acc += p[(size_t)c * stride];
    float h = fmaxf(acc, 0.f);
    unsigned short hi, lo;
    bf16split(h, hi, lo);
    size_t idx = fragIdx(f, lane);
    Ahi[idx] = hi;
    Alo[idx] = lo;
}

// ---------------------------------------------------------------------------
// Kernel 4: final reduce + bias (no ReLU) -> d_out [64][1000].
// (verified in round 1; unchanged)
// ---------------------------------------------------------------------------
__global__ __launch_bounds__(256) void reduce_out_kernel(
    const float* __restrict__ part, const float* __restrict__ bias,
    float* __restrict__ out, int nchunk)
{
    int idx = blockIdx.x * 256 + threadIdx.x;    // f*64 + b
    if (idx >= OO * 64) return;
    int f = idx >> 6, b = idx & 63;
    float v = bias[f];
    const float* p = part + (size_t)f * 64 + b;
    size_t stride = (size_t)OO * 64;
    #pragma unroll 8
    for (int c = 0; c < nchunk; ++c)
        v += p[(size_t)c * stride];
    out[(size_t)b * OO + f] = v;
}

// ---------------------------------------------------------------------------
extern "C" void kernel_launch(void* const* d_in, const int* in_sizes, int n_in,
                              void* d_out, int out_size, void* d_ws, size_t ws_size,
                              hipStream_t stream) {
    const float* x    = (const float*)d_in[0];
    const float* xart = (const float*)d_in[1];
    const int*   ll   = (const int*)d_in[2];
    const float* w1   = (const float*)d_in[3];
    const float* b1   = (const float*)d_in[4];
    const float* w2   = (const float*)d_in[5];
    const float* b2   = (const float*)d_in[6];
    const float* w3   = (const float*)d_in[7];
    const float* b3   = (const float*)d_in[8];
    float* out = (float*)d_out;

    // workspace: 3 A-frag pairs (512 KiB each plane) then split-K partials
    unsigned short* A1h = (unsigned short*)d_ws;
    unsigned short* A1l = A1h + (size_t)DD * 64;
    unsigned short* A2h = A1l + (size_t)DD * 64;
    unsigned short* A2l = A2h + (size_t)FF * 64;
    unsigned short* A3h = A2l + (size_t)FF * 64;
    unsigned short* A3l = A3h + (size_t)FF * 64;
    float* part = (float*)(A3l + (size_t)FF * 64);

    int nk1 = 16, nk3 = 32;                 // part: 16 MiB / 8 MiB
    size_t fragBytes = (size_t)6 * DD * 64 * sizeof(unsigned short);  // 3 MiB
    if (ws_size < fragBytes + ((size_t)nk1 * FF * 64 * sizeof(float))) {
        nk1 = 8; nk3 = 16;                  // 8 MiB / 4 MiB fallback
    }
    int kchunk1 = DD / nk1;                 // 256
    int kchunk3 = FF / nk3;                 // 128

    // 1) ragged max-pool -> A1 fragments
    pool_kernel<<<2048, 256, 0, stream>>>(x, xart, ll, A1h, A1l);

    // 2) h1 = relu(pooled @ w1 + b1) -> A2 fragments
    gemm_mfma<<<dim3(FF / 64, nk1), 256, 0, stream>>>(A1h, A1l, w1, part, FF, kchunk1);
    reduce_bias_relu_frag<<<FF / 4, 256, 0, stream>>>(part, b1, A2h, A2l, nk1, FF);

    // 3) h2 = relu(h1 @ w2 + b2) -> A3 fragments
    gemm_mfma<<<dim3(FF / 64, nk1), 256, 0, stream>>>(A2h, A2l, w2, part, FF, kchunk1);
    reduce_bias_relu_frag<<<FF / 4, 256, 0, stream>>>(part, b2, A3h, A3l, nk1, FF);

    // 4) out = h2 @ w3 + b3   (16 f-blocks, tail cols masked)
    gemm_mfma<<<dim3((OO + 63) / 64, nk3), 256, 0, stream>>>(A3h, A3l, w3, part, OO, kchunk3);
    reduce_out_kernel<<<(BB * OO + 255) / 256, 256, 0, stream>>>(part, b3, out, nk3);
}